// Round 1
// baseline (379.884 us; speedup 1.0000x reference)
//
#include <hip/hip_runtime.h>
#include <hip/hip_bf16.h>
#include <cmath>

#define B_ROWS 2048
#define D_DIM 512
#define C_COLS 10572

// ---------------------------------------------------------------------------
// Kernel 1: reciprocal L2 norm per row (D=512). One block of 256 per row.
// ---------------------------------------------------------------------------
__global__ __launch_bounds__(256) void rownorm_kernel(const float* __restrict__ x,
                                                      float* __restrict__ rn) {
    int row = blockIdx.x;
    const float* xr = x + (size_t)row * D_DIM;
    int tid = threadIdx.x;
    float a = xr[tid];
    float b = xr[tid + 256];
    float ss = a * a + b * b;
#pragma unroll
    for (int off = 32; off > 0; off >>= 1) ss += __shfl_down(ss, off);
    __shared__ float red[4];
    int wave = tid >> 6;
    if ((tid & 63) == 0) red[wave] = ss;
    __syncthreads();
    if (tid == 0) {
        float t = red[0] + red[1] + red[2] + red[3];
        rn[row] = 1.0f / sqrtf(t);
    }
}

// ---------------------------------------------------------------------------
// Kernel 2: f32 GEMM  cos[i][j] = dot(feat[i]*rnf[i], weights[j]*rnw[j])
// 64x64 tile, 256 threads, 4x4 microtile, K-step 32, LDS-staged.
// Also writes logits = scale*cos.
// ---------------------------------------------------------------------------
__global__ __launch_bounds__(256) void gemm_cos_kernel(const float* __restrict__ feat,
                                                       const float* __restrict__ weights,
                                                       const float* __restrict__ rnf,
                                                       const float* __restrict__ rnw,
                                                       float* __restrict__ cosm,
                                                       float* __restrict__ logits,
                                                       float scale) {
    __shared__ float As[32][68];  // [k][m], padded to 68 (16B-aligned rows, conflict-free)
    __shared__ float Bs[32][68];  // [k][n]
    int tid = threadIdx.x;
    int tx = tid & 15, ty = tid >> 4;
    int row0 = blockIdx.y * 64;
    int col0 = blockIdx.x * 64;
    float acc[4][4] = {};
    for (int k0 = 0; k0 < D_DIM; k0 += 32) {
#pragma unroll
        for (int it = 0; it < 2; ++it) {
            int idx = tid + it * 256;
            int r = idx >> 3;          // 0..63
            int c4 = (idx & 7) << 2;   // 0,4,..,28
            const float4 va = *(const float4*)&feat[(size_t)(row0 + r) * D_DIM + k0 + c4];
            float sa = rnf[row0 + r];
            As[c4 + 0][r] = va.x * sa;
            As[c4 + 1][r] = va.y * sa;
            As[c4 + 2][r] = va.z * sa;
            As[c4 + 3][r] = va.w * sa;
            int wrow = col0 + r;
            float4 vb = make_float4(0.f, 0.f, 0.f, 0.f);
            float sb = 0.f;
            if (wrow < C_COLS) {
                vb = *(const float4*)&weights[(size_t)wrow * D_DIM + k0 + c4];
                sb = rnw[wrow];
            }
            Bs[c4 + 0][r] = vb.x * sb;
            Bs[c4 + 1][r] = vb.y * sb;
            Bs[c4 + 2][r] = vb.z * sb;
            Bs[c4 + 3][r] = vb.w * sb;
        }
        __syncthreads();
#pragma unroll
        for (int k = 0; k < 32; ++k) {
            const float4 a = *(const float4*)&As[k][ty << 2];
            const float4 b = *(const float4*)&Bs[k][tx << 2];
            float av[4] = {a.x, a.y, a.z, a.w};
            float bv[4] = {b.x, b.y, b.z, b.w};
#pragma unroll
            for (int i = 0; i < 4; ++i)
#pragma unroll
                for (int j = 0; j < 4; ++j)
                    acc[i][j] = fmaf(av[i], bv[j], acc[i][j]);
        }
        __syncthreads();
    }
#pragma unroll
    for (int i = 0; i < 4; ++i) {
        int row = row0 + (ty << 2) + i;
#pragma unroll
        for (int j = 0; j < 4; ++j) {
            int col = col0 + (tx << 2) + j;
            if (col < C_COLS) {
                size_t o = (size_t)row * C_COLS + col;
                float v = acc[i][j];
                cosm[o] = v;
                logits[o] = scale * v;
            }
        }
    }
}

// ---------------------------------------------------------------------------
// Kernel 3: per-row softmax stats + ground-truth column rescale.
// One block of 256 per row. Two passes over the row (L2/L3-resident).
// ---------------------------------------------------------------------------
__global__ __launch_bounds__(256) void row_fix_kernel(const float* __restrict__ cosm,
                                                      const int* __restrict__ label,
                                                      float* __restrict__ logits,
                                                      float* __restrict__ pgt,
                                                      float* __restrict__ bvals,
                                                      float scale) {
    int row = blockIdx.x;
    const float* cr = cosm + (size_t)row * C_COLS;
    int tid = threadIdx.x;
    __shared__ float red[4];
    __shared__ float bcast;

    float lmax = -1e30f;
    for (int j = tid; j < C_COLS; j += 256) lmax = fmaxf(lmax, cr[j]);
#pragma unroll
    for (int off = 32; off > 0; off >>= 1) lmax = fmaxf(lmax, __shfl_down(lmax, off));
    int wave = tid >> 6;
    if ((tid & 63) == 0) red[wave] = lmax;
    __syncthreads();
    if (tid == 0) bcast = fmaxf(fmaxf(red[0], red[1]), fmaxf(red[2], red[3]));
    __syncthreads();
    float m = scale * bcast;  // max logit

    float ls = 0.f;
    for (int j = tid; j < C_COLS; j += 256) ls += expf(scale * cr[j] - m);
#pragma unroll
    for (int off = 32; off > 0; off >>= 1) ls += __shfl_down(ls, off);
    if ((tid & 63) == 0) red[wave] = ls;
    __syncthreads();
    if (tid == 0) {
        float S = red[0] + red[1] + red[2] + red[3];
        int lbl = label[row];
        float cg = cr[lbl];
        float egt = expf(scale * cg - m);
        float p = egt / S;
        float Bv = expf(scale * cg) * (1.0f / p - 1.0f);
        const float PI = 3.14159265358979323846f;
        float theta = acosf(cg);
        float dth = (theta >= 0.5f * PI) ? (0.5f * PI - 0.01f) : theta;
        float val = logf(Bv * (PI / (2.0f * dth) - 1.0f));  // == s * cos_gt
        logits[(size_t)row * C_COLS + lbl] = val;
        pgt[row] = p;
        bvals[row] = Bv;
    }
}

// ---------------------------------------------------------------------------
// Kernel 4: final scalar reductions (avg/min/max p, B_avg, two zeros).
// ---------------------------------------------------------------------------
__global__ __launch_bounds__(256) void finalize_kernel(const float* __restrict__ pgt,
                                                       const float* __restrict__ bvals,
                                                       float* __restrict__ tail,
                                                       float scale) {
    int tid = threadIdx.x;
    float s = 0.f, mn = 1e30f, mx = -1e30f, sb = 0.f;
    for (int i = tid; i < B_ROWS; i += 256) {
        float p = pgt[i];
        s += p;
        mn = fminf(mn, p);
        mx = fmaxf(mx, p);
        sb += bvals[i];
    }
#pragma unroll
    for (int off = 32; off > 0; off >>= 1) {
        s += __shfl_down(s, off);
        mn = fminf(mn, __shfl_down(mn, off));
        mx = fmaxf(mx, __shfl_down(mx, off));
        sb += __shfl_down(sb, off);
    }
    __shared__ float rs[4], rmn[4], rmx[4], rsb[4];
    int wave = tid >> 6;
    if ((tid & 63) == 0) { rs[wave] = s; rmn[wave] = mn; rmx[wave] = mx; rsb[wave] = sb; }
    __syncthreads();
    if (tid == 0) {
        float S = 0.f, MN = 1e30f, MX = -1e30f, SB = 0.f;
        for (int w = 0; w < 4; ++w) {
            S += rs[w]; MN = fminf(MN, rmn[w]); MX = fmaxf(MX, rmx[w]); SB += rsb[w];
        }
        const float PI = 3.14159265358979323846f;
        tail[0] = S / (float)B_ROWS;                       // avg_p
        tail[1] = MN;                                      // min_p
        tail[2] = MX;                                      // max_p
        float meanB = SB / (float)B_ROWS;
        tail[3] = acosf(logf(meanB / (float)(C_COLS - 1)) / scale) / PI * 180.0f;  // B_avg
        tail[4] = 0.0f;
        tail[5] = 0.0f;
    }
}

// ---------------------------------------------------------------------------
extern "C" void kernel_launch(void* const* d_in, const int* in_sizes, int n_in,
                              void* d_out, int out_size, void* d_ws, size_t ws_size,
                              hipStream_t stream) {
    const float* feat = (const float*)d_in[0];
    const int* label = (const int*)d_in[1];
    const float* weights = (const float*)d_in[2];

    float* out = (float*)d_out;
    float* cos_out = out;
    float* logits_out = out + (size_t)B_ROWS * C_COLS;
    float* tail = out + (size_t)2 * B_ROWS * C_COLS;

    float* ws = (float*)d_ws;
    float* rnf = ws;                    // 2048
    float* rnw = rnf + B_ROWS;          // 10572
    float* pgt = rnw + C_COLS;          // 2048
    float* bv = pgt + B_ROWS;           // 2048

    double scale_d = std::sqrt(2.0) * std::log((double)(C_COLS - 1));
    float scale = (float)scale_d;

    rownorm_kernel<<<B_ROWS, 256, 0, stream>>>(feat, rnf);
    rownorm_kernel<<<C_COLS, 256, 0, stream>>>(weights, rnw);

    dim3 grid((C_COLS + 63) / 64, B_ROWS / 64);
    gemm_cos_kernel<<<grid, 256, 0, stream>>>(feat, weights, rnf, rnw, cos_out, logits_out,
                                              scale);

    row_fix_kernel<<<B_ROWS, 256, 0, stream>>>(cos_out, label, logits_out, pgt, bv, scale);
    finalize_kernel<<<1, 256, 0, stream>>>(pgt, bv, tail, scale);
}

// Round 2
// 172.527 us; speedup vs baseline: 2.2019x; 2.2019x over previous
//
#include <hip/hip_runtime.h>
#include <hip/hip_bf16.h>
#include <cmath>

#define B_ROWS 2048
#define D_DIM 512
#define C_COLS 10572
#define WPAD 10624  // 83 * 128, zero-padded weight rows

#define BM 128
#define BN 128
#define BK 32

typedef __attribute__((ext_vector_type(8))) short short8;
typedef __attribute__((ext_vector_type(4))) float f32x4;

// byte-address XOR swizzle (involution: source bits 7-9, target bits 4-6)
__device__ __host__ inline int swz(int a) { return a ^ (((a >> 7) & 7) << 4); }

__device__ inline void load_lds16(const void* g, const void* l) {
    __builtin_amdgcn_global_load_lds(
        (const __attribute__((address_space(1))) unsigned int*)g,
        (__attribute__((address_space(3))) unsigned int*)l, 16, 0, 0);
}

// ---------------------------------------------------------------------------
// Fused row-normalize + bf16 hi/lo split. One block of 256 per row (D=512).
// Rows >= nrows are zero-filled (weight padding).
// ---------------------------------------------------------------------------
__global__ __launch_bounds__(256) void normsplit_kernel(const float* __restrict__ x,
                                                        int nrows,
                                                        __hip_bfloat16* __restrict__ hi,
                                                        __hip_bfloat16* __restrict__ lo) {
    int row = blockIdx.x;
    int tid = threadIdx.x;
    size_t base = (size_t)row * D_DIM;
    if (row >= nrows) {
        __hip_bfloat16 z = __float2bfloat16(0.0f);
        hi[base + tid] = z;
        hi[base + tid + 256] = z;
        lo[base + tid] = z;
        lo[base + tid + 256] = z;
        return;
    }
    const float* xr = x + base;
    float a = xr[tid];
    float b = xr[tid + 256];
    float ss = a * a + b * b;
#pragma unroll
    for (int off = 32; off > 0; off >>= 1) ss += __shfl_down(ss, off);
    __shared__ float red[4];
    __shared__ float rbc;
    if ((tid & 63) == 0) red[tid >> 6] = ss;
    __syncthreads();
    if (tid == 0) rbc = 1.0f / sqrtf(red[0] + red[1] + red[2] + red[3]);
    __syncthreads();
    float rn = rbc;
    float va = a * rn;
    float vb = b * rn;
    __hip_bfloat16 ha = __float2bfloat16(va);
    __hip_bfloat16 hb = __float2bfloat16(vb);
    hi[base + tid] = ha;
    hi[base + tid + 256] = hb;
    lo[base + tid] = __float2bfloat16(va - __bfloat162float(ha));
    lo[base + tid + 256] = __float2bfloat16(vb - __bfloat162float(hb));
}

// ---------------------------------------------------------------------------
// MFMA GEMM: cos = A_norm @ W_norm^T via bf16 hi/lo 3-pass split.
// 128x128 tile, BK=32, 4 waves (2x2), each wave 64x64 = 4x4 x mfma_16x16x32.
// LDS XOR-swizzled (T2), global_load_lds width-16 staging (pre-swizzled src).
// ---------------------------------------------------------------------------
__global__ __launch_bounds__(256) void gemm_mfma_kernel(
    const __hip_bfloat16* __restrict__ fhi, const __hip_bfloat16* __restrict__ flo,
    const __hip_bfloat16* __restrict__ whi, const __hip_bfloat16* __restrict__ wlo,
    float* __restrict__ cosm, float* __restrict__ logits, float scale) {
    __shared__ __hip_bfloat16 As[BM * BK];  // 8 KB, logical [row][k] row-major, 64B rows
    __shared__ __hip_bfloat16 Bs[BN * BK];  // 8 KB

    int tid = threadIdx.x;
    int lane = tid & 63;
    int w = tid >> 6;
    int wr = w >> 1, wc = w & 1;

    // XCD-aware bijective block swizzle (nwg = 83*16 = 1328, divisible by 8)
    int orig = blockIdx.y * gridDim.x + blockIdx.x;
    int nwg = gridDim.x * gridDim.y;
    int cpx = nwg >> 3;
    int s = (orig & 7) * cpx + (orig >> 3);
    int bx = s % gridDim.x;
    int by = s / gridDim.x;
    int row0 = by * BM;
    int col0 = bx * BN;

    // staging source coords: LDS linear dest o -> global element at swz(o)
    int grow[2], gcol[2], ldsw[2];
#pragma unroll
    for (int i = 0; i < 2; ++i) {
        int o = i * 4096 + tid * 16;
        int q = swz(o);
        grow[i] = q >> 6;
        gcol[i] = (q & 63) >> 1;
        ldsw[i] = i * 4096 + w * 1024;  // wave-uniform LDS base
    }

    // fragment ds_read offsets (swizzled), fixed across K-steps
    int r = lane & 15, kb = lane >> 4;
    int aoff[4], boff[4];
#pragma unroll
    for (int m = 0; m < 4; ++m) {
        aoff[m] = swz((wr * 64 + m * 16 + r) * 64 + kb * 16);
        boff[m] = swz((wc * 64 + m * 16 + r) * 64 + kb * 16);
    }

    f32x4 acc[4][4] = {};

#pragma unroll
    for (int p = 0; p < 3; ++p) {
        const __hip_bfloat16* Ap = ((p == 2) ? flo : fhi) + (size_t)row0 * D_DIM;
        const __hip_bfloat16* Bp = ((p == 1) ? wlo : whi) + (size_t)col0 * D_DIM;
        for (int k0 = 0; k0 < D_DIM; k0 += BK) {
#pragma unroll
            for (int i = 0; i < 2; ++i) {
                load_lds16(Ap + (size_t)grow[i] * D_DIM + k0 + gcol[i],
                           (const char*)As + ldsw[i]);
                load_lds16(Bp + (size_t)grow[i] * D_DIM + k0 + gcol[i],
                           (const char*)Bs + ldsw[i]);
            }
            __syncthreads();
            short8 af[4], bf[4];
#pragma unroll
            for (int m = 0; m < 4; ++m) af[m] = *(const short8*)((const char*)As + aoff[m]);
#pragma unroll
            for (int n = 0; n < 4; ++n) bf[n] = *(const short8*)((const char*)Bs + boff[n]);
#pragma unroll
            for (int m = 0; m < 4; ++m)
#pragma unroll
                for (int n = 0; n < 4; ++n)
                    acc[m][n] = __builtin_amdgcn_mfma_f32_16x16x32_bf16(af[m], bf[n],
                                                                        acc[m][n], 0, 0, 0);
            __syncthreads();
        }
    }

    // epilogue: C/D layout col=lane&15, row=(lane>>4)*4+reg
    int crow = (lane >> 4) * 2; (void)crow;
#pragma unroll
    for (int m = 0; m < 4; ++m) {
#pragma unroll
        for (int n = 0; n < 4; ++n) {
#pragma unroll
            for (int j = 0; j < 4; ++j) {
                int rrow = row0 + wr * 64 + m * 16 + (lane >> 4) * 4 + j;
                int ccol = col0 + wc * 64 + n * 16 + (lane & 15);
                if (ccol < C_COLS) {
                    size_t o = (size_t)rrow * C_COLS + ccol;
                    float v = acc[m][n][j];
                    cosm[o] = v;
                    logits[o] = scale * v;
                }
            }
        }
    }
}

// ---------------------------------------------------------------------------
// Per-row softmax stats + ground-truth column rescale (float4 reads, __expf).
// ---------------------------------------------------------------------------
__global__ __launch_bounds__(256) void row_fix_kernel(const float* __restrict__ cosm,
                                                      const int* __restrict__ label,
                                                      float* __restrict__ logits,
                                                      float* __restrict__ pgt,
                                                      float* __restrict__ bvals,
                                                      float scale) {
    int row = blockIdx.x;
    int tid = threadIdx.x;
    const float4* cr4 = (const float4*)(cosm + (size_t)row * C_COLS);
    const int N4 = C_COLS / 4;  // 2643
    __shared__ float red[4];
    __shared__ float bcast;

    float lmax = -1e30f;
    for (int j = tid; j < N4; j += 256) {
        float4 v = cr4[j];
        lmax = fmaxf(lmax, fmaxf(fmaxf(v.x, v.y), fmaxf(v.z, v.w)));
    }
#pragma unroll
    for (int off = 32; off > 0; off >>= 1) lmax = fmaxf(lmax, __shfl_down(lmax, off));
    int wave = tid >> 6;
    if ((tid & 63) == 0) red[wave] = lmax;
    __syncthreads();
    if (tid == 0) bcast = fmaxf(fmaxf(red[0], red[1]), fmaxf(red[2], red[3]));
    __syncthreads();
    float m = scale * bcast;

    float ls = 0.f;
    for (int j = tid; j < N4; j += 256) {
        float4 v = cr4[j];
        ls += __expf(scale * v.x - m) + __expf(scale * v.y - m) + __expf(scale * v.z - m) +
              __expf(scale * v.w - m);
    }
#pragma unroll
    for (int off = 32; off > 0; off >>= 1) ls += __shfl_down(ls, off);
    if ((tid & 63) == 0) red[wave] = ls;
    __syncthreads();
    if (tid == 0) {
        float S = red[0] + red[1] + red[2] + red[3];
        int lbl = label[row];
        float cg = cosm[(size_t)row * C_COLS + lbl];
        float egt = __expf(scale * cg - m);
        float p = egt / S;
        float Bv = expf(scale * cg) * (1.0f / p - 1.0f);
        const float PI = 3.14159265358979323846f;
        float theta = acosf(cg);
        float dth = (theta >= 0.5f * PI) ? (0.5f * PI - 0.01f) : theta;
        float val = logf(Bv * (PI / (2.0f * dth) - 1.0f));  // == s * cos_gt
        logits[(size_t)row * C_COLS + lbl] = val;
        pgt[row] = p;
        bvals[row] = Bv;
    }
}

// ---------------------------------------------------------------------------
// Final scalar reductions.
// ---------------------------------------------------------------------------
__global__ __launch_bounds__(256) void finalize_kernel(const float* __restrict__ pgt,
                                                       const float* __restrict__ bvals,
                                                       float* __restrict__ tail,
                                                       float scale) {
    int tid = threadIdx.x;
    float s = 0.f, mn = 1e30f, mx = -1e30f, sb = 0.f;
    for (int i = tid; i < B_ROWS; i += 256) {
        float p = pgt[i];
        s += p;
        mn = fminf(mn, p);
        mx = fmaxf(mx, p);
        sb += bvals[i];
    }
#pragma unroll
    for (int off = 32; off > 0; off >>= 1) {
        s += __shfl_down(s, off);
        mn = fminf(mn, __shfl_down(mn, off));
        mx = fmaxf(mx, __shfl_down(mx, off));
        sb += __shfl_down(sb, off);
    }
    __shared__ float rs[4], rmn[4], rmx[4], rsb[4];
    int wave = tid >> 6;
    if ((tid & 63) == 0) { rs[wave] = s; rmn[wave] = mn; rmx[wave] = mx; rsb[wave] = sb; }
    __syncthreads();
    if (tid == 0) {
        float S = 0.f, MN = 1e30f, MX = -1e30f, SB = 0.f;
        for (int ww = 0; ww < 4; ++ww) {
            S += rs[ww]; MN = fminf(MN, rmn[ww]); MX = fmaxf(MX, rmx[ww]); SB += rsb[ww];
        }
        const float PI = 3.14159265358979323846f;
        tail[0] = S / (float)B_ROWS;
        tail[1] = MN;
        tail[2] = MX;
        float meanB = SB / (float)B_ROWS;
        tail[3] = acosf(logf(meanB / (float)(C_COLS - 1)) / scale) / PI * 180.0f;
        tail[4] = 0.0f;
        tail[5] = 0.0f;
    }
}

// ---------------------------------------------------------------------------
// Fallback f32 GEMM path (proven in R1) if ws_size is too small for bf16 split.
// ---------------------------------------------------------------------------
__global__ __launch_bounds__(256) void rownorm_kernel(const float* __restrict__ x,
                                                      float* __restrict__ rn) {
    int row = blockIdx.x;
    const float* xr = x + (size_t)row * D_DIM;
    int tid = threadIdx.x;
    float a = xr[tid];
    float b = xr[tid + 256];
    float ss = a * a + b * b;
#pragma unroll
    for (int off = 32; off > 0; off >>= 1) ss += __shfl_down(ss, off);
    __shared__ float red[4];
    int wave = tid >> 6;
    if ((tid & 63) == 0) red[wave] = ss;
    __syncthreads();
    if (tid == 0) rn[row] = 1.0f / sqrtf(red[0] + red[1] + red[2] + red[3]);
}

__global__ __launch_bounds__(256) void gemm_cos_kernel(const float* __restrict__ feat,
                                                       const float* __restrict__ weights,
                                                       const float* __restrict__ rnf,
                                                       const float* __restrict__ rnw,
                                                       float* __restrict__ cosm,
                                                       float* __restrict__ logits,
                                                       float scale) {
    __shared__ float Asf[32][68];
    __shared__ float Bsf[32][68];
    int tid = threadIdx.x;
    int tx = tid & 15, ty = tid >> 4;
    int row0 = blockIdx.y * 64;
    int col0 = blockIdx.x * 64;
    float acc[4][4] = {};
    for (int k0 = 0; k0 < D_DIM; k0 += 32) {
#pragma unroll
        for (int it = 0; it < 2; ++it) {
            int idx = tid + it * 256;
            int rr = idx >> 3;
            int c4 = (idx & 7) << 2;
            const float4 va = *(const float4*)&feat[(size_t)(row0 + rr) * D_DIM + k0 + c4];
            float sa = rnf[row0 + rr];
            Asf[c4 + 0][rr] = va.x * sa;
            Asf[c4 + 1][rr] = va.y * sa;
            Asf[c4 + 2][rr] = va.z * sa;
            Asf[c4 + 3][rr] = va.w * sa;
            int wrow = col0 + rr;
            float4 vb = make_float4(0.f, 0.f, 0.f, 0.f);
            float sb = 0.f;
            if (wrow < C_COLS) {
                vb = *(const float4*)&weights[(size_t)wrow * D_DIM + k0 + c4];
                sb = rnw[wrow];
            }
            Bsf[c4 + 0][rr] = vb.x * sb;
            Bsf[c4 + 1][rr] = vb.y * sb;
            Bsf[c4 + 2][rr] = vb.z * sb;
            Bsf[c4 + 3][rr] = vb.w * sb;
        }
        __syncthreads();
#pragma unroll
        for (int k = 0; k < 32; ++k) {
            const float4 a = *(const float4*)&Asf[k][ty << 2];
            const float4 b = *(const float4*)&Bsf[k][tx << 2];
            float av[4] = {a.x, a.y, a.z, a.w};
            float bv[4] = {b.x, b.y, b.z, b.w};
#pragma unroll
            for (int i = 0; i < 4; ++i)
#pragma unroll
                for (int j = 0; j < 4; ++j) acc[i][j] = fmaf(av[i], bv[j], acc[i][j]);
        }
        __syncthreads();
    }
#pragma unroll
    for (int i = 0; i < 4; ++i) {
        int row = row0 + (ty << 2) + i;
#pragma unroll
        for (int j = 0; j < 4; ++j) {
            int col = col0 + (tx << 2) + j;
            if (col < C_COLS) {
                size_t o = (size_t)row * C_COLS + col;
                float v = acc[i][j];
                cosm[o] = v;
                logits[o] = scale * v;
            }
        }
    }
}

// ---------------------------------------------------------------------------
extern "C" void kernel_launch(void* const* d_in, const int* in_sizes, int n_in,
                              void* d_out, int out_size, void* d_ws, size_t ws_size,
                              hipStream_t stream) {
    const float* feat = (const float*)d_in[0];
    const int* label = (const int*)d_in[1];
    const float* weights = (const float*)d_in[2];

    float* out = (float*)d_out;
    float* cos_out = out;
    float* logits_out = out + (size_t)B_ROWS * C_COLS;
    float* tail = out + (size_t)2 * B_ROWS * C_COLS;

    double scale_d = std::sqrt(2.0) * std::log((double)(C_COLS - 1));
    float scale = (float)scale_d;

    const size_t fhalf = (size_t)B_ROWS * D_DIM * sizeof(__hip_bfloat16);   // 2 MB
    const size_t whalf = (size_t)WPAD * D_DIM * sizeof(__hip_bfloat16);     // 10.875 MB
    const size_t need = 2 * fhalf + 2 * whalf + 2 * B_ROWS * sizeof(float) + 1024;

    if (ws_size >= need) {
        char* wsb = (char*)d_ws;
        __hip_bfloat16* fhi = (__hip_bfloat16*)wsb;
        __hip_bfloat16* flo = (__hip_bfloat16*)(wsb + fhalf);
        __hip_bfloat16* whi = (__hip_bfloat16*)(wsb + 2 * fhalf);
        __hip_bfloat16* wlo = (__hip_bfloat16*)(wsb + 2 * fhalf + whalf);
        float* pgt = (float*)(wsb + 2 * fhalf + 2 * whalf);
        float* bv = pgt + B_ROWS;

        normsplit_kernel<<<B_ROWS, 256, 0, stream>>>(feat, B_ROWS, fhi, flo);
        normsplit_kernel<<<WPAD, 256, 0, stream>>>(weights, C_COLS, whi, wlo);

        dim3 grid(WPAD / BN, B_ROWS / BM);  // 83 x 16
        gemm_mfma_kernel<<<grid, 256, 0, stream>>>(fhi, flo, whi, wlo, cos_out, logits_out,
                                                   scale);

        row_fix_kernel<<<B_ROWS, 256, 0, stream>>>(cos_out, label, logits_out, pgt, bv,
                                                   scale);
        finalize_kernel<<<1, 256, 0, stream>>>(pgt, bv, tail, scale);
    } else {
        float* ws = (float*)d_ws;
        float* rnf = ws;
        float* rnw = rnf + B_ROWS;
        float* pgt = rnw + C_COLS;
        float* bv = pgt + B_ROWS;

        rownorm_kernel<<<B_ROWS, 256, 0, stream>>>(feat, rnf);
        rownorm_kernel<<<C_COLS, 256, 0, stream>>>(weights, rnw);
        dim3 grid((C_COLS + 63) / 64, B_ROWS / 64);
        gemm_cos_kernel<<<grid, 256, 0, stream>>>(feat, weights, rnf, rnw, cos_out,
                                                  logits_out, scale);
        row_fix_kernel<<<B_ROWS, 256, 0, stream>>>(cos_out, label, logits_out, pgt, bv,
                                                   scale);
        finalize_kernel<<<1, 256, 0, stream>>>(pgt, bv, tail, scale);
    }
}

// Round 3
// 142.234 us; speedup vs baseline: 2.6708x; 1.2130x over previous
//
#include <hip/hip_runtime.h>
#include <hip/hip_bf16.h>
#include <cmath>

#define B_ROWS 2048
#define D_DIM 512
#define C_COLS 10572
#define WPAD 10624  // 83 * 128, zero-padded weight rows

#define BM 128
#define BN 128
#define BK 32

typedef __attribute__((ext_vector_type(8))) short short8;
typedef __attribute__((ext_vector_type(4))) float f32x4;

// byte-address XOR swizzle (involution: source bits 7-9 -> target bits 4-6)
__device__ __host__ inline int swz(int a) { return a ^ (((a >> 7) & 7) << 4); }

__device__ inline void load_lds16(const void* g, const void* l) {
    __builtin_amdgcn_global_load_lds(
        (const __attribute__((address_space(1))) unsigned int*)g,
        (__attribute__((address_space(3))) unsigned int*)l, 16, 0, 0);
}

// ---------------------------------------------------------------------------
// Fused row-normalize + bf16 hi/lo split. One block of 256 per row (D=512).
// Rows >= nrows are zero-filled (weight padding). Optionally zeroes rowsum.
// ---------------------------------------------------------------------------
__global__ __launch_bounds__(256) void normsplit_kernel(const float* __restrict__ x,
                                                        int nrows,
                                                        __hip_bfloat16* __restrict__ hi,
                                                        __hip_bfloat16* __restrict__ lo,
                                                        float* __restrict__ rowsum) {
    int row = blockIdx.x;
    int tid = threadIdx.x;
    size_t base = (size_t)row * D_DIM;
    if (rowsum && tid == 0) rowsum[row] = 0.0f;
    if (row >= nrows) {
        __hip_bfloat16 z = __float2bfloat16(0.0f);
        hi[base + tid] = z;
        hi[base + tid + 256] = z;
        lo[base + tid] = z;
        lo[base + tid + 256] = z;
        return;
    }
    const float* xr = x + base;
    float a = xr[tid];
    float b = xr[tid + 256];
    float ss = a * a + b * b;
#pragma unroll
    for (int off = 32; off > 0; off >>= 1) ss += __shfl_down(ss, off);
    __shared__ float red[4];
    __shared__ float rbc;
    if ((tid & 63) == 0) red[tid >> 6] = ss;
    __syncthreads();
    if (tid == 0) rbc = 1.0f / sqrtf(red[0] + red[1] + red[2] + red[3]);
    __syncthreads();
    float rn = rbc;
    float va = a * rn;
    float vb = b * rn;
    __hip_bfloat16 ha = __float2bfloat16(va);
    __hip_bfloat16 hb = __float2bfloat16(vb);
    hi[base + tid] = ha;
    hi[base + tid + 256] = hb;
    lo[base + tid] = __float2bfloat16(va - __bfloat162float(ha));
    lo[base + tid + 256] = __float2bfloat16(vb - __bfloat162float(hb));
}

// ---------------------------------------------------------------------------
// Fused MFMA GEMM: cos = A @ W^T via bf16 hi/lo split, single K-loop,
// 3 MFMA terms per k-step (hi.hi + hi.lo + lo.hi). 128x128 tile, BK=32,
// 4 waves (2x2), each wave 64x64 = 4x4 x mfma_16x16x32.
// Epilogue: writes cos & scale*cos, accumulates per-row sum(exp(scale*cos))
// via 16-lane xor-reduce + atomicAdd (no max-shift needed: |logit|<=13.2).
// ---------------------------------------------------------------------------
__global__ __launch_bounds__(256) void gemm_fused_kernel(
    const __hip_bfloat16* __restrict__ fhi, const __hip_bfloat16* __restrict__ flo,
    const __hip_bfloat16* __restrict__ whi, const __hip_bfloat16* __restrict__ wlo,
    float* __restrict__ cosm, float* __restrict__ logits, float* __restrict__ rowsum,
    float scale) {
    __shared__ __hip_bfloat16 Ah[BM * BK];  // 8 KB each, [row][k] row-major, 64B rows
    __shared__ __hip_bfloat16 Al[BM * BK];
    __shared__ __hip_bfloat16 Bh[BN * BK];
    __shared__ __hip_bfloat16 Bl[BN * BK];

    int tid = threadIdx.x;
    int lane = tid & 63;
    int w = tid >> 6;
    int wr = w >> 1, wc = w & 1;

    // XCD-aware bijective block swizzle (nwg = 83*16 = 1328, divisible by 8)
    int orig = blockIdx.y * gridDim.x + blockIdx.x;
    int nwg = gridDim.x * gridDim.y;
    int cpx = nwg >> 3;
    int s = (orig & 7) * cpx + (orig >> 3);
    int bx = s % gridDim.x;
    int by = s / gridDim.x;
    int row0 = by * BM;
    int col0 = bx * BN;

    // staging: LDS linear dest o -> global element at swz(o)
    int grow[2], gcol[2], ldsw[2];
#pragma unroll
    for (int i = 0; i < 2; ++i) {
        int o = i * 4096 + tid * 16;
        int q = swz(o);
        grow[i] = q >> 6;
        gcol[i] = (q & 63) >> 1;
        ldsw[i] = i * 4096 + w * 1024;  // wave-uniform LDS base
    }

    // fragment ds_read offsets (swizzled), fixed across K-steps
    int r = lane & 15, kb = lane >> 4;
    int aoff[4], boff[4];
#pragma unroll
    for (int m = 0; m < 4; ++m) {
        aoff[m] = swz((wr * 64 + m * 16 + r) * 64 + kb * 16);
        boff[m] = swz((wc * 64 + m * 16 + r) * 64 + kb * 16);
    }

    const __hip_bfloat16* Afh = fhi + (size_t)row0 * D_DIM;
    const __hip_bfloat16* Afl = flo + (size_t)row0 * D_DIM;
    const __hip_bfloat16* Bwh = whi + (size_t)col0 * D_DIM;
    const __hip_bfloat16* Bwl = wlo + (size_t)col0 * D_DIM;

    f32x4 acc[4][4] = {};

    for (int k0 = 0; k0 < D_DIM; k0 += BK) {
#pragma unroll
        for (int i = 0; i < 2; ++i) {
            size_t go = (size_t)grow[i] * D_DIM + k0 + gcol[i];
            load_lds16(Afh + go, (const char*)Ah + ldsw[i]);
            load_lds16(Afl + go, (const char*)Al + ldsw[i]);
            load_lds16(Bwh + go, (const char*)Bh + ldsw[i]);
            load_lds16(Bwl + go, (const char*)Bl + ldsw[i]);
        }
        __syncthreads();
        short8 afh[4], bfh[4], bfl[4];
#pragma unroll
        for (int m = 0; m < 4; ++m) afh[m] = *(const short8*)((const char*)Ah + aoff[m]);
#pragma unroll
        for (int n = 0; n < 4; ++n) bfh[n] = *(const short8*)((const char*)Bh + boff[n]);
#pragma unroll
        for (int m = 0; m < 4; ++m)
#pragma unroll
            for (int n = 0; n < 4; ++n)
                acc[m][n] = __builtin_amdgcn_mfma_f32_16x16x32_bf16(afh[m], bfh[n],
                                                                    acc[m][n], 0, 0, 0);
#pragma unroll
        for (int n = 0; n < 4; ++n) bfl[n] = *(const short8*)((const char*)Bl + boff[n]);
#pragma unroll
        for (int m = 0; m < 4; ++m)
#pragma unroll
            for (int n = 0; n < 4; ++n)
                acc[m][n] = __builtin_amdgcn_mfma_f32_16x16x32_bf16(afh[m], bfl[n],
                                                                    acc[m][n], 0, 0, 0);
        short8 afl[4];
#pragma unroll
        for (int m = 0; m < 4; ++m) afl[m] = *(const short8*)((const char*)Al + aoff[m]);
#pragma unroll
        for (int m = 0; m < 4; ++m)
#pragma unroll
            for (int n = 0; n < 4; ++n)
                acc[m][n] = __builtin_amdgcn_mfma_f32_16x16x32_bf16(afl[m], bfh[n],
                                                                    acc[m][n], 0, 0, 0);
        __syncthreads();
    }

    // epilogue: C/D layout col=lane&15, row=(lane>>4)*4+reg.
    // Lanes sharing (lane>>4) hold the same rows, partitioned over cols.
#pragma unroll
    for (int m = 0; m < 4; ++m) {
#pragma unroll
        for (int j = 0; j < 4; ++j) {
            int rrow = row0 + wr * 64 + m * 16 + (lane >> 4) * 4 + j;
            float se = 0.f;
#pragma unroll
            for (int n = 0; n < 4; ++n) {
                int ccol = col0 + wc * 64 + n * 16 + (lane & 15);
                float v = acc[m][n][j];
                if (ccol < C_COLS) {
                    size_t o = (size_t)rrow * C_COLS + ccol;
                    cosm[o] = v;
                    logits[o] = scale * v;
                    se += __expf(scale * v);
                }
            }
#pragma unroll
            for (int off = 1; off < 16; off <<= 1) se += __shfl_xor(se, off);
            if ((lane & 15) == 0) atomicAdd(&rowsum[rrow], se);
        }
    }
}

// ---------------------------------------------------------------------------
// Per-row ground-truth fix from precomputed row sums. One thread per row.
// ---------------------------------------------------------------------------
__global__ __launch_bounds__(256) void gt_fix_kernel(const float* __restrict__ cosm,
                                                     const int* __restrict__ label,
                                                     const float* __restrict__ rowsum,
                                                     float* __restrict__ logits,
                                                     float* __restrict__ pgt,
                                                     float* __restrict__ bvals,
                                                     float scale) {
    int row = blockIdx.x * blockDim.x + threadIdx.x;
    if (row >= B_ROWS) return;
    int lbl = label[row];
    float cg = cosm[(size_t)row * C_COLS + lbl];
    float S = rowsum[row];
    float e = expf(scale * cg);
    float p = e / S;
    float Bv = S - e;  // == exp(logit_gt)*(1/p - 1) exactly
    const float PI = 3.14159265358979323846f;
    float theta = acosf(cg);
    float dth = (theta >= 0.5f * PI) ? (0.5f * PI - 0.01f) : theta;
    float val = logf(Bv * (PI / (2.0f * dth) - 1.0f));  // == s * cos_gt
    logits[(size_t)row * C_COLS + lbl] = val;
    pgt[row] = p;
    bvals[row] = Bv;
}

// ---------------------------------------------------------------------------
// Final scalar reductions.
// ---------------------------------------------------------------------------
__global__ __launch_bounds__(256) void finalize_kernel(const float* __restrict__ pgt,
                                                       const float* __restrict__ bvals,
                                                       float* __restrict__ tail,
                                                       float scale) {
    int tid = threadIdx.x;
    float s = 0.f, mn = 1e30f, mx = -1e30f, sb = 0.f;
    for (int i = tid; i < B_ROWS; i += 256) {
        float p = pgt[i];
        s += p;
        mn = fminf(mn, p);
        mx = fmaxf(mx, p);
        sb += bvals[i];
    }
#pragma unroll
    for (int off = 32; off > 0; off >>= 1) {
        s += __shfl_down(s, off);
        mn = fminf(mn, __shfl_down(mn, off));
        mx = fmaxf(mx, __shfl_down(mx, off));
        sb += __shfl_down(sb, off);
    }
    __shared__ float rs[4], rmn[4], rmx[4], rsb[4];
    int wave = tid >> 6;
    if ((tid & 63) == 0) { rs[wave] = s; rmn[wave] = mn; rmx[wave] = mx; rsb[wave] = sb; }
    __syncthreads();
    if (tid == 0) {
        float S = 0.f, MN = 1e30f, MX = -1e30f, SB = 0.f;
        for (int ww = 0; ww < 4; ++ww) {
            S += rs[ww]; MN = fminf(MN, rmn[ww]); MX = fmaxf(MX, rmx[ww]); SB += rsb[ww];
        }
        const float PI = 3.14159265358979323846f;
        tail[0] = S / (float)B_ROWS;
        tail[1] = MN;
        tail[2] = MX;
        float meanB = SB / (float)B_ROWS;
        tail[3] = acosf(logf(meanB / (float)(C_COLS - 1)) / scale) / PI * 180.0f;
        tail[4] = 0.0f;
        tail[5] = 0.0f;
    }
}

// ---------------------------------------------------------------------------
// Fallback f32 path (proven in R1) if ws_size is too small for the bf16 split.
// ---------------------------------------------------------------------------
__global__ __launch_bounds__(256) void rownorm_kernel(const float* __restrict__ x,
                                                      float* __restrict__ rn) {
    int row = blockIdx.x;
    const float* xr = x + (size_t)row * D_DIM;
    int tid = threadIdx.x;
    float a = xr[tid];
    float b = xr[tid + 256];
    float ss = a * a + b * b;
#pragma unroll
    for (int off = 32; off > 0; off >>= 1) ss += __shfl_down(ss, off);
    __shared__ float red[4];
    if ((tid & 63) == 0) red[tid >> 6] = ss;
    __syncthreads();
    if (tid == 0) rn[row] = 1.0f / sqrtf(red[0] + red[1] + red[2] + red[3]);
}

__global__ __launch_bounds__(256) void gemm_cos_kernel(const float* __restrict__ feat,
                                                       const float* __restrict__ weights,
                                                       const float* __restrict__ rnf,
                                                       const float* __restrict__ rnw,
                                                       float* __restrict__ cosm,
                                                       float* __restrict__ logits,
                                                       float scale) {
    __shared__ float Asf[32][68];
    __shared__ float Bsf[32][68];
    int tid = threadIdx.x;
    int tx = tid & 15, ty = tid >> 4;
    int row0 = blockIdx.y * 64;
    int col0 = blockIdx.x * 64;
    float acc[4][4] = {};
    for (int k0 = 0; k0 < D_DIM; k0 += 32) {
#pragma unroll
        for (int it = 0; it < 2; ++it) {
            int idx = tid + it * 256;
            int rr = idx >> 3;
            int c4 = (idx & 7) << 2;
            const float4 va = *(const float4*)&feat[(size_t)(row0 + rr) * D_DIM + k0 + c4];
            float sa = rnf[row0 + rr];
            Asf[c4 + 0][rr] = va.x * sa;
            Asf[c4 + 1][rr] = va.y * sa;
            Asf[c4 + 2][rr] = va.z * sa;
            Asf[c4 + 3][rr] = va.w * sa;
            int wrow = col0 + rr;
            float4 vb = make_float4(0.f, 0.f, 0.f, 0.f);
            float sb = 0.f;
            if (wrow < C_COLS) {
                vb = *(const float4*)&weights[(size_t)wrow * D_DIM + k0 + c4];
                sb = rnw[wrow];
            }
            Bsf[c4 + 0][rr] = vb.x * sb;
            Bsf[c4 + 1][rr] = vb.y * sb;
            Bsf[c4 + 2][rr] = vb.z * sb;
            Bsf[c4 + 3][rr] = vb.w * sb;
        }
        __syncthreads();
#pragma unroll
        for (int k = 0; k < 32; ++k) {
            const float4 a = *(const float4*)&Asf[k][ty << 2];
            const float4 b = *(const float4*)&Bsf[k][tx << 2];
            float av[4] = {a.x, a.y, a.z, a.w};
            float bv[4] = {b.x, b.y, b.z, b.w};
#pragma unroll
            for (int i = 0; i < 4; ++i)
#pragma unroll
                for (int j = 0; j < 4; ++j) acc[i][j] = fmaf(av[i], bv[j], acc[i][j]);
        }
        __syncthreads();
    }
#pragma unroll
    for (int i = 0; i < 4; ++i) {
        int row = row0 + (ty << 2) + i;
#pragma unroll
        for (int j = 0; j < 4; ++j) {
            int col = col0 + (tx << 2) + j;
            if (col < C_COLS) {
                size_t o = (size_t)row * C_COLS + col;
                float v = acc[i][j];
                cosm[o] = v;
                logits[o] = scale * v;
            }
        }
    }
}

__global__ __launch_bounds__(256) void row_fix_kernel(const float* __restrict__ cosm,
                                                      const int* __restrict__ label,
                                                      float* __restrict__ logits,
                                                      float* __restrict__ pgt,
                                                      float* __restrict__ bvals,
                                                      float scale) {
    int row = blockIdx.x;
    int tid = threadIdx.x;
    const float4* cr4 = (const float4*)(cosm + (size_t)row * C_COLS);
    const int N4 = C_COLS / 4;
    __shared__ float red[4];
    __shared__ float bcast;

    float lmax = -1e30f;
    for (int j = tid; j < N4; j += 256) {
        float4 v = cr4[j];
        lmax = fmaxf(lmax, fmaxf(fmaxf(v.x, v.y), fmaxf(v.z, v.w)));
    }
#pragma unroll
    for (int off = 32; off > 0; off >>= 1) lmax = fmaxf(lmax, __shfl_down(lmax, off));
    int wave = tid >> 6;
    if ((tid & 63) == 0) red[wave] = lmax;
    __syncthreads();
    if (tid == 0) bcast = fmaxf(fmaxf(red[0], red[1]), fmaxf(red[2], red[3]));
    __syncthreads();
    float m = scale * bcast;

    float ls = 0.f;
    for (int j = tid; j < N4; j += 256) {
        float4 v = cr4[j];
        ls += __expf(scale * v.x - m) + __expf(scale * v.y - m) + __expf(scale * v.z - m) +
              __expf(scale * v.w - m);
    }
#pragma unroll
    for (int off = 32; off > 0; off >>= 1) ls += __shfl_down(ls, off);
    if ((tid & 63) == 0) red[wave] = ls;
    __syncthreads();
    if (tid == 0) {
        float S = red[0] + red[1] + red[2] + red[3];
        int lbl = label[row];
        float cg = cosm[(size_t)row * C_COLS + lbl];
        float egt = __expf(scale * cg - m);
        float p = egt / S;
        float Bv = expf(scale * cg) * (1.0f / p - 1.0f);
        const float PI = 3.14159265358979323846f;
        float theta = acosf(cg);
        float dth = (theta >= 0.5f * PI) ? (0.5f * PI - 0.01f) : theta;
        float val = logf(Bv * (PI / (2.0f * dth) - 1.0f));
        logits[(size_t)row * C_COLS + lbl] = val;
        pgt[row] = p;
        bvals[row] = Bv;
    }
}

// ---------------------------------------------------------------------------
extern "C" void kernel_launch(void* const* d_in, const int* in_sizes, int n_in,
                              void* d_out, int out_size, void* d_ws, size_t ws_size,
                              hipStream_t stream) {
    const float* feat = (const float*)d_in[0];
    const int* label = (const int*)d_in[1];
    const float* weights = (const float*)d_in[2];

    float* out = (float*)d_out;
    float* cos_out = out;
    float* logits_out = out + (size_t)B_ROWS * C_COLS;
    float* tail = out + (size_t)2 * B_ROWS * C_COLS;

    double scale_d = std::sqrt(2.0) * std::log((double)(C_COLS - 1));
    float scale = (float)scale_d;

    const size_t fhalf = (size_t)B_ROWS * D_DIM * sizeof(__hip_bfloat16);   // 2 MB
    const size_t whalf = (size_t)WPAD * D_DIM * sizeof(__hip_bfloat16);     // 10.875 MB
    const size_t need = 2 * fhalf + 2 * whalf + 3 * B_ROWS * sizeof(float) + 1024;

    if (ws_size >= need) {
        char* wsb = (char*)d_ws;
        __hip_bfloat16* fhi = (__hip_bfloat16*)wsb;
        __hip_bfloat16* flo = (__hip_bfloat16*)(wsb + fhalf);
        __hip_bfloat16* whi = (__hip_bfloat16*)(wsb + 2 * fhalf);
        __hip_bfloat16* wlo = (__hip_bfloat16*)(wsb + 2 * fhalf + whalf);
        float* rowsum = (float*)(wsb + 2 * fhalf + 2 * whalf);
        float* pgt = rowsum + B_ROWS;
        float* bv = pgt + B_ROWS;

        normsplit_kernel<<<B_ROWS, 256, 0, stream>>>(feat, B_ROWS, fhi, flo, rowsum);
        normsplit_kernel<<<WPAD, 256, 0, stream>>>(weights, C_COLS, whi, wlo, nullptr);

        dim3 grid(WPAD / BN, B_ROWS / BM);  // 83 x 16
        gemm_fused_kernel<<<grid, 256, 0, stream>>>(fhi, flo, whi, wlo, cos_out,
                                                    logits_out, rowsum, scale);

        gt_fix_kernel<<<(B_ROWS + 255) / 256, 256, 0, stream>>>(cos_out, label, rowsum,
                                                                logits_out, pgt, bv, scale);
        finalize_kernel<<<1, 256, 0, stream>>>(pgt, bv, tail, scale);
    } else {
        float* ws = (float*)d_ws;
        float* rnf = ws;
        float* rnw = rnf + B_ROWS;
        float* pgt = rnw + C_COLS;
        float* bv = pgt + B_ROWS;

        rownorm_kernel<<<B_ROWS, 256, 0, stream>>>(feat, rnf);
        rownorm_kernel<<<C_COLS, 256, 0, stream>>>(weights, rnw);
        dim3 grid((C_COLS + 63) / 64, B_ROWS / 64);
        gemm_cos_kernel<<<grid, 256, 0, stream>>>(feat, weights, rnf, rnw, cos_out,
                                                  logits_out, scale);
        row_fix_kernel<<<B_ROWS, 256, 0, stream>>>(cos_out, label, logits_out, pgt, bv,
                                                   scale);
        finalize_kernel<<<1, 256, 0, stream>>>(pgt, bv, tail, scale);
    }
}

// Round 5
// 82.523 us; speedup vs baseline: 4.6034x; 1.7236x over previous
//
#include <hip/hip_runtime.h>
#include <hip/hip_bf16.h>
#include <cmath>

#define B_ROWS 2048
#define D_DIM 512
#define C_COLS 10572
#define WPAD 10624  // 83 * 128, zero-padded weight rows

#define BM 128
#define BN 128
#define BK 32
#define NSTEP (D_DIM / BK)  // 16

typedef __attribute__((ext_vector_type(8))) short short8;
typedef __attribute__((ext_vector_type(4))) float f32x4;

// byte-address XOR swizzle (involution: byte bits 7-9 -> bits 4-6)
__device__ __host__ inline int swz(int a) { return a ^ (((a >> 7) & 7) << 4); }

__device__ inline void load_lds16(const void* g, const void* l) {
    __builtin_amdgcn_global_load_lds(
        (const __attribute__((address_space(1))) unsigned int*)g,
        (__attribute__((address_space(3))) unsigned int*)l, 16, 0, 0);
}

// ---------------------------------------------------------------------------
// Fused row-normalize + bf16 cast. One block of 256 per row (D=512).
// Rows >= nrows are zero-filled (weight padding). Optionally zeroes rowsum.
// ---------------------------------------------------------------------------
__global__ __launch_bounds__(256) void normsplit_kernel(const float* __restrict__ x,
                                                        int nrows,
                                                        __hip_bfloat16* __restrict__ hi,
                                                        float* __restrict__ rowsum) {
    int row = blockIdx.x;
    int tid = threadIdx.x;
    size_t base = (size_t)row * D_DIM;
    if (rowsum && tid == 0) rowsum[row] = 0.0f;
    if (row >= nrows) {
        __hip_bfloat16 z = __float2bfloat16(0.0f);
        hi[base + tid] = z;
        hi[base + tid + 256] = z;
        return;
    }
    const float* xr = x + base;
    float a = xr[tid];
    float b = xr[tid + 256];
    float ss = a * a + b * b;
#pragma unroll
    for (int off = 32; off > 0; off >>= 1) ss += __shfl_down(ss, off);
    __shared__ float red[4];
    __shared__ float rbc;
    if ((tid & 63) == 0) red[tid >> 6] = ss;
    __syncthreads();
    if (tid == 0) rbc = 1.0f / sqrtf(red[0] + red[1] + red[2] + red[3]);
    __syncthreads();
    float rn = rbc;
    hi[base + tid] = __float2bfloat16(a * rn);
    hi[base + tid + 256] = __float2bfloat16(b * rn);
}

// ---------------------------------------------------------------------------
// bf16 MFMA GEMM: cos = A @ W^T. 128x128 tile, BK=32, 4 waves (2x2),
// each wave 64x64 = 4x4 x mfma_16x16x32. Double-buffered LDS, 2-phase
// pipeline (stage next K-step before compute of current, 1 barrier/step).
// LDS XOR-swizzled (T2), global_load_lds width-16 with pre-swizzled source.
// Epilogue: writes cos & scale*cos, accumulates per-row sum(exp(scale*cos))
// via 16-lane xor-reduce + atomicAdd (no max-shift needed: |logit|<=13.2).
// ---------------------------------------------------------------------------
__global__ __launch_bounds__(256) void gemm_bf16_kernel(
    const __hip_bfloat16* __restrict__ fhi, const __hip_bfloat16* __restrict__ whi,
    float* __restrict__ cosm, float* __restrict__ logits, float* __restrict__ rowsum,
    float scale) {
    __shared__ __hip_bfloat16 Abuf[2][BM * BK];  // 8 KB each
    __shared__ __hip_bfloat16 Bbuf[2][BN * BK];

    int tid = threadIdx.x;
    int lane = tid & 63;
    int w = tid >> 6;
    int wr = w >> 1, wc = w & 1;

    // XCD chunking (8 chunks of 166) + column-major walk within chunk:
    // 16 consecutive blocks share one W-panel (L2 reuse); fhi stays L2-resident.
    int orig = blockIdx.y * gridDim.x + blockIdx.x;
    int s = (orig & 7) * 166 + (orig >> 3);  // nwg = 1328 = 8*166, bijective
    int by = s & 15;   // 0..15
    int bx = s >> 4;   // 0..82
    int row0 = by * BM;
    int col0 = bx * BN;

    // staging: LDS linear dest byte o -> global element at swz(o)
    int grow[2], gcol[2], ldsw[2];
#pragma unroll
    for (int i = 0; i < 2; ++i) {
        int o = i * 4096 + tid * 16;
        int q = swz(o);
        grow[i] = q >> 6;          // tile row
        gcol[i] = (q & 63) >> 1;   // element within 32-wide k
        ldsw[i] = i * 4096 + w * 1024;  // wave-uniform LDS base
    }

    // fragment ds_read offsets (swizzled), fixed across K-steps
    int r = lane & 15, kb = lane >> 4;
    int aoff[4], boff[4];
#pragma unroll
    for (int m = 0; m < 4; ++m) {
        aoff[m] = swz((wr * 64 + m * 16 + r) * 64 + kb * 16);
        boff[m] = swz((wc * 64 + m * 16 + r) * 64 + kb * 16);
    }

    const __hip_bfloat16* Ap = fhi + (size_t)row0 * D_DIM;
    const __hip_bfloat16* Bp = whi + (size_t)col0 * D_DIM;

    f32x4 acc[4][4] = {};

    // prologue: stage K-step 0 into buffer 0
#pragma unroll
    for (int i = 0; i < 2; ++i) {
        size_t go = (size_t)grow[i] * D_DIM + gcol[i];
        load_lds16(Ap + go, (const char*)Abuf[0] + ldsw[i]);
        load_lds16(Bp + go, (const char*)Bbuf[0] + ldsw[i]);
    }
    __syncthreads();

    int cur = 0;
    for (int t = 0; t < NSTEP; ++t) {
        if (t < NSTEP - 1) {
            int k0 = (t + 1) * BK;
#pragma unroll
            for (int i = 0; i < 2; ++i) {
                size_t go = (size_t)grow[i] * D_DIM + k0 + gcol[i];
                load_lds16(Ap + go, (const char*)Abuf[cur ^ 1] + ldsw[i]);
                load_lds16(Bp + go, (const char*)Bbuf[cur ^ 1] + ldsw[i]);
            }
        }
        short8 af[4], bf[4];
#pragma unroll
        for (int m = 0; m < 4; ++m)
            af[m] = *(const short8*)((const char*)Abuf[cur] + aoff[m]);
#pragma unroll
        for (int n = 0; n < 4; ++n)
            bf[n] = *(const short8*)((const char*)Bbuf[cur] + boff[n]);
        __builtin_amdgcn_s_setprio(1);
#pragma unroll
        for (int m = 0; m < 4; ++m)
#pragma unroll
            for (int n = 0; n < 4; ++n)
                acc[m][n] = __builtin_amdgcn_mfma_f32_16x16x32_bf16(af[m], bf[n],
                                                                    acc[m][n], 0, 0, 0);
        __builtin_amdgcn_s_setprio(0);
        __syncthreads();  // drains vmcnt (prefetch landed under MFMA phase)
        cur ^= 1;
    }

    // epilogue: C/D layout col=lane&15, row=(lane>>4)*4+reg.
#pragma unroll
    for (int m = 0; m < 4; ++m) {
#pragma unroll
        for (int j = 0; j < 4; ++j) {
            int rrow = row0 + wr * 64 + m * 16 + (lane >> 4) * 4 + j;
            float se = 0.f;
#pragma unroll
            for (int n = 0; n < 4; ++n) {
                int ccol = col0 + wc * 64 + n * 16 + (lane & 15);
                float v = acc[m][n][j];
                if (ccol < C_COLS) {
                    size_t o = (size_t)rrow * C_COLS + ccol;
                    cosm[o] = v;
                    logits[o] = scale * v;
                    se += __expf(scale * v);
                }
            }
#pragma unroll
            for (int off = 1; off < 16; off <<= 1) se += __shfl_xor(se, off);
            if ((lane & 15) == 0) atomicAdd(&rowsum[rrow], se);
        }
    }
}

// ---------------------------------------------------------------------------
// Exact f32 recompute of cos_gt for each row (one wave per row, 4 rows/block):
// cg = <feat[row], weights[lbl]> / (||feat[row]|| * ||weights[lbl]||).
// Patches cosm gt column, writes gt logit via the cancellation-free identity
// pi/(2*theta) - 1 == asin(cg)/acos(cg) for cg > 0. Writes pgt/bvals.
// ---------------------------------------------------------------------------
__global__ __launch_bounds__(256) void gt_fix_kernel(
    const float* __restrict__ feat, const float* __restrict__ weights,
    const int* __restrict__ label, const float* __restrict__ rowsum,
    float* __restrict__ cosm, float* __restrict__ logits,
    float* __restrict__ pgt, float* __restrict__ bvals, float scale) {
    int row = blockIdx.x * 4 + (threadIdx.x >> 6);
    int lane = threadIdx.x & 63;
    if (row >= B_ROWS) return;
    int lbl = label[row];
    const float4* f4 = (const float4*)(feat + (size_t)row * D_DIM);
    const float4* w4 = (const float4*)(weights + (size_t)lbl * D_DIM);
    float ff = 0.f, ww = 0.f, fw = 0.f;
#pragma unroll
    for (int i = 0; i < 2; ++i) {
        float4 a = f4[lane + i * 64];
        float4 b = w4[lane + i * 64];
        ff += a.x * a.x + a.y * a.y + a.z * a.z + a.w * a.w;
        ww += b.x * b.x + b.y * b.y + b.z * b.z + b.w * b.w;
        fw += a.x * b.x + a.y * b.y + a.z * b.z + a.w * b.w;
    }
#pragma unroll
    for (int off = 32; off > 0; off >>= 1) {
        ff += __shfl_xor(ff, off);
        ww += __shfl_xor(ww, off);
        fw += __shfl_xor(fw, off);
    }
    if (lane == 0) {
        float cg = fw / (sqrtf(ff) * sqrtf(ww));
        float S = rowsum[row];
        float e = expf(scale * cg);
        float p = e / S;
        float Bv = S - e;  // == exp(logit_gt)*(1/p - 1) exactly
        const float PI = 3.14159265358979323846f;
        float marg;
        if (cg > 0.f) {
            marg = asinf(cg) / acosf(cg);  // == pi/(2*theta)-1, no cancellation
        } else {
            float dth = 0.5f * PI - 0.01f;
            marg = PI / (2.0f * dth) - 1.0f;
        }
        size_t o = (size_t)row * C_COLS + lbl;
        cosm[o] = cg;
        logits[o] = logf(Bv * marg);
        pgt[row] = p;
        bvals[row] = Bv;
    }
}

// ---------------------------------------------------------------------------
// Final scalar reductions, one block of 256.
// ---------------------------------------------------------------------------
__global__ __launch_bounds__(256) void finalize_kernel(const float* __restrict__ pgt,
                                                       const float* __restrict__ bvals,
                                                       float* __restrict__ tail,
                                                       float scale) {
    int tid = threadIdx.x;
    float s = 0.f, mn = 1e30f, mx = -1e30f, sb = 0.f;
    for (int i = tid; i < B_ROWS; i += 256) {
        float p = pgt[i];
        s += p;
        mn = fminf(mn, p);
        mx = fmaxf(mx, p);
        sb += bvals[i];
    }
#pragma unroll
    for (int off = 32; off > 0; off >>= 1) {
        s += __shfl_down(s, off);
        mn = fminf(mn, __shfl_down(mn, off));
        mx = fmaxf(mx, __shfl_down(mx, off));
        sb += __shfl_down(sb, off);
    }
    __shared__ float rs[4], rmn[4], rmx[4], rsb[4];
    int wave = tid >> 6;
    if ((tid & 63) == 0) { rs[wave] = s; rmn[wave] = mn; rmx[wave] = mx; rsb[wave] = sb; }
    __syncthreads();
    if (tid == 0) {
        float S = 0.f, MN = 1e30f, MX = -1e30f, SB = 0.f;
        for (int ww = 0; ww < 4; ++ww) {
            S += rs[ww]; MN = fminf(MN, rmn[ww]); MX = fmaxf(MX, rmx[ww]); SB += rsb[ww];
        }
        const float PI = 3.14159265358979323846f;
        tail[0] = S / (float)B_ROWS;
        tail[1] = MN;
        tail[2] = MX;
        float meanB = SB / (float)B_ROWS;
        tail[3] = acosf(logf(meanB / (float)(C_COLS - 1)) / scale) / PI * 180.0f;
        tail[4] = 0.0f;
        tail[5] = 0.0f;
    }
}

// ---------------------------------------------------------------------------
extern "C" void kernel_launch(void* const* d_in, const int* in_sizes, int n_in,
                              void* d_out, int out_size, void* d_ws, size_t ws_size,
                              hipStream_t stream) {
    const float* feat = (const float*)d_in[0];
    const int* label = (const int*)d_in[1];
    const float* weights = (const float*)d_in[2];

    float* out = (float*)d_out;
    float* cos_out = out;
    float* logits_out = out + (size_t)B_ROWS * C_COLS;
    float* tail = out + (size_t)2 * B_ROWS * C_COLS;

    double scale_d = std::sqrt(2.0) * std::log((double)(C_COLS - 1));
    float scale = (float)scale_d;

    const size_t fsz = (size_t)B_ROWS * D_DIM * sizeof(__hip_bfloat16);  // 2 MB
    const size_t wsz = (size_t)WPAD * D_DIM * sizeof(__hip_bfloat16);    // 10.875 MB
    char* wsb = (char*)d_ws;
    __hip_bfloat16* fhi = (__hip_bfloat16*)wsb;
    __hip_bfloat16* whi = (__hip_bfloat16*)(wsb + fsz);
    float* rowsum = (float*)(wsb + fsz + wsz);
    float* pgt = rowsum + B_ROWS;
    float* bv = pgt + B_ROWS;

    normsplit_kernel<<<B_ROWS, 256, 0, stream>>>(feat, B_ROWS, fhi, rowsum);
    normsplit_kernel<<<WPAD, 256, 0, stream>>>(weights, C_COLS, whi, nullptr);

    dim3 grid(WPAD / BN, B_ROWS / BM);  // 83 x 16 = 1328
    gemm_bf16_kernel<<<grid, 256, 0, stream>>>(fhi, whi, cos_out, logits_out, rowsum,
                                               scale);

    gt_fix_kernel<<<B_ROWS / 4, 256, 0, stream>>>(feat, weights, label, rowsum, cos_out,
                                                  logits_out, pgt, bv, scale);
    finalize_kernel<<<1, 256, 0, stream>>>(pgt, bv, tail, scale);
}

// Round 6
// 75.523 us; speedup vs baseline: 5.0300x; 1.0927x over previous
//
#include <hip/hip_runtime.h>
#include <hip/hip_bf16.h>
#include <cmath>

#define B_ROWS 2048
#define D_DIM 512
#define C_COLS 10572
#define WPAD 10624  // 83 * 128, zero-padded weight rows

#define BM 128
#define BN 128
#define BK 32
#define NSTEP (D_DIM / BK)  // 16

typedef __attribute__((ext_vector_type(8))) short short8;
typedef __attribute__((ext_vector_type(4))) float f32x4;

// byte-address XOR swizzle (involution: byte bits 7-9 -> bits 4-6)
__device__ __host__ inline int swz(int a) { return a ^ (((a >> 7) & 7) << 4); }

__device__ inline void load_lds16(const void* g, const void* l) {
    __builtin_amdgcn_global_load_lds(
        (const __attribute__((address_space(1))) unsigned int*)g,
        (__attribute__((address_space(3))) unsigned int*)l, 16, 0, 0);
}

// ---------------------------------------------------------------------------
// Fused normalize + bf16 cast for BOTH matrices. One wave per row, 4 rows
// per block. float4 loads, short8 (16B) stores. Rows >= C_COLS in the weight
// range are zero-filled. Also zeroes rowsum for feat rows.
// ---------------------------------------------------------------------------
__global__ __launch_bounds__(256) void normcast_kernel(
    const float* __restrict__ feat, const float* __restrict__ wts,
    __hip_bfloat16* __restrict__ fhi, __hip_bfloat16* __restrict__ whi,
    float* __restrict__ rowsum) {
    int idx = blockIdx.x * 4 + (threadIdx.x >> 6);
    int lane = threadIdx.x & 63;
    const float* src;
    __hip_bfloat16* dst;
    if (idx < B_ROWS) {
        src = feat + (size_t)idx * D_DIM;
        dst = fhi + (size_t)idx * D_DIM;
        if (lane == 0) rowsum[idx] = 0.0f;
    } else {
        int r = idx - B_ROWS;
        dst = whi + (size_t)r * D_DIM;
        if (r >= C_COLS) {
            short8 z = {0, 0, 0, 0, 0, 0, 0, 0};
            *(short8*)(dst + lane * 8) = z;
            return;
        }
        src = wts + (size_t)r * D_DIM;
    }
    float4 a = *(const float4*)(src + lane * 8);
    float4 b = *(const float4*)(src + lane * 8 + 4);
    float ss = a.x * a.x + a.y * a.y + a.z * a.z + a.w * a.w +
               b.x * b.x + b.y * b.y + b.z * b.z + b.w * b.w;
#pragma unroll
    for (int off = 32; off > 0; off >>= 1) ss += __shfl_xor(ss, off);
    float rn = 1.0f / sqrtf(ss);
    float v[8] = {a.x * rn, a.y * rn, a.z * rn, a.w * rn,
                  b.x * rn, b.y * rn, b.z * rn, b.w * rn};
    short8 o;
#pragma unroll
    for (int k = 0; k < 8; ++k) {
        __hip_bfloat16 h = __float2bfloat16(v[k]);
        o[k] = *reinterpret_cast<short*>(&h);
    }
    *(short8*)(dst + lane * 8) = o;
}

// ---------------------------------------------------------------------------
// bf16 MFMA GEMM: cos = A @ W^T. 128x128 tile, BK=32, 4 waves (2x2),
// each wave 64x64 = 4x4 x mfma_16x16x32. Triple-buffered LDS,
// prefetch-distance-2 pipeline with counted s_waitcnt vmcnt(4) + raw
// s_barrier (loads stay in flight across barriers — T4). LDS XOR-swizzled.
// Epilogue: writes cos & scale*cos, accumulates per-row sum(exp(scale*cos))
// via 16-lane xor-reduce + atomicAdd (no max-shift: |logit|<=13.2).
// ---------------------------------------------------------------------------
__global__ __launch_bounds__(256) void gemm_bf16_kernel(
    const __hip_bfloat16* __restrict__ fhi, const __hip_bfloat16* __restrict__ whi,
    float* __restrict__ cosm, float* __restrict__ logits, float* __restrict__ rowsum,
    float scale) {
    __shared__ __hip_bfloat16 Abuf[3][BM * BK];  // 8 KB each -> 24 KB
    __shared__ __hip_bfloat16 Bbuf[3][BN * BK];  // 24 KB (48 KB total)

    int tid = threadIdx.x;
    int lane = tid & 63;
    int w = tid >> 6;
    int wr = w >> 1, wc = w & 1;

    // XCD chunking (8 chunks of 166) + column-major walk within chunk:
    // 16 consecutive blocks share one W-panel (L2 reuse); fhi stays L2-resident.
    int orig = blockIdx.y * gridDim.x + blockIdx.x;
    int s = (orig & 7) * 166 + (orig >> 3);  // nwg = 1328 = 8*166, bijective
    int by = s & 15;   // 0..15
    int bx = s >> 4;   // 0..82
    int row0 = by * BM;
    int col0 = bx * BN;

    // staging: LDS linear dest byte o -> global element at swz(o)
    int grow[2], gcol[2], ldsw[2];
#pragma unroll
    for (int i = 0; i < 2; ++i) {
        int o = i * 4096 + tid * 16;
        int q = swz(o);
        grow[i] = q >> 6;          // tile row
        gcol[i] = (q & 63) >> 1;   // element within 32-wide k
        ldsw[i] = i * 4096 + w * 1024;  // wave-uniform LDS base
    }

    // fragment ds_read offsets (swizzled), fixed across K-steps
    int r = lane & 15, kb = lane >> 4;
    int aoff[4], boff[4];
#pragma unroll
    for (int m = 0; m < 4; ++m) {
        aoff[m] = swz((wr * 64 + m * 16 + r) * 64 + kb * 16);
        boff[m] = swz((wc * 64 + m * 16 + r) * 64 + kb * 16);
    }

    const __hip_bfloat16* Ap = fhi + (size_t)row0 * D_DIM;
    const __hip_bfloat16* Bp = whi + (size_t)col0 * D_DIM;

    auto stage = [&](int k0, int b) {
#pragma unroll
        for (int i = 0; i < 2; ++i) {
            size_t go = (size_t)grow[i] * D_DIM + k0 + gcol[i];
            load_lds16(Ap + go, (const char*)&Abuf[b][0] + ldsw[i]);
            load_lds16(Bp + go, (const char*)&Bbuf[b][0] + ldsw[i]);
        }
    };

    f32x4 acc[4][4] = {};

    // prologue: stage K-steps 0 and 1; wait only for step 0 (4 newest in flight)
    stage(0, 0);
    stage(BK, 1);
    asm volatile("s_waitcnt vmcnt(4)" ::: "memory");
    __builtin_amdgcn_s_barrier();
    __builtin_amdgcn_sched_barrier(0);

    int cur = 0, sb = 2;
    for (int t = 0; t < NSTEP; ++t) {
        if (t + 2 < NSTEP) stage((t + 2) * BK, sb);
        const char* Ab = (const char*)&Abuf[cur][0];
        const char* Bb = (const char*)&Bbuf[cur][0];
        short8 af[4], bf[4];
#pragma unroll
        for (int m = 0; m < 4; ++m) af[m] = *(const short8*)(Ab + aoff[m]);
#pragma unroll
        for (int n = 0; n < 4; ++n) bf[n] = *(const short8*)(Bb + boff[n]);
        __builtin_amdgcn_s_setprio(1);
#pragma unroll
        for (int m = 0; m < 4; ++m)
#pragma unroll
            for (int n = 0; n < 4; ++n)
                acc[m][n] = __builtin_amdgcn_mfma_f32_16x16x32_bf16(af[m], bf[n],
                                                                    acc[m][n], 0, 0, 0);
        __builtin_amdgcn_s_setprio(0);
        // counted wait: leave the 4 just-issued (t+2) loads in flight;
        // the (t+1) buffer's 4 older loads must have landed.
        if (t + 2 < NSTEP)
            asm volatile("s_waitcnt vmcnt(4)" ::: "memory");
        else
            asm volatile("s_waitcnt vmcnt(0)" ::: "memory");
        __builtin_amdgcn_s_barrier();
        __builtin_amdgcn_sched_barrier(0);
        cur = (cur == 2) ? 0 : cur + 1;
        sb = (sb == 2) ? 0 : sb + 1;
    }

    // epilogue: C/D layout col=lane&15, row=(lane>>4)*4+reg.
#pragma unroll
    for (int m = 0; m < 4; ++m) {
#pragma unroll
        for (int j = 0; j < 4; ++j) {
            int rrow = row0 + wr * 64 + m * 16 + (lane >> 4) * 4 + j;
            float se = 0.f;
#pragma unroll
            for (int n = 0; n < 4; ++n) {
                int ccol = col0 + wc * 64 + n * 16 + (lane & 15);
                float v = acc[m][n][j];
                if (ccol < C_COLS) {
                    size_t o = (size_t)rrow * C_COLS + ccol;
                    cosm[o] = v;
                    logits[o] = scale * v;
                    se += __expf(scale * v);
                }
            }
#pragma unroll
            for (int off = 1; off < 16; off <<= 1) se += __shfl_xor(se, off);
            if ((lane & 15) == 0) atomicAdd(&rowsum[rrow], se);
        }
    }
}

// ---------------------------------------------------------------------------
// Exact f32 recompute of cos_gt for each row (one wave per row, 4 rows/block):
// cg = <feat[row], weights[lbl]> / (||feat[row]|| * ||weights[lbl]||).
// Patches cosm gt column, writes gt logit via the cancellation-free identity
// pi/(2*theta) - 1 == asin(cg)/acos(cg) for cg > 0. Writes pgt/bvals.
// ---------------------------------------------------------------------------
__global__ __launch_bounds__(256) void gt_fix_kernel(
    const float* __restrict__ feat, const float* __restrict__ weights,
    const int* __restrict__ label, const float* __restrict__ rowsum,
    float* __restrict__ cosm, float* __restrict__ logits,
    float* __restrict__ pgt, float* __restrict__ bvals, float scale) {
    int row = blockIdx.x * 4 + (threadIdx.x >> 6);
    int lane = threadIdx.x & 63;
    if (row >= B_ROWS) return;
    int lbl = label[row];
    const float4* f4 = (const float4*)(feat + (size_t)row * D_DIM);
    const float4* w4 = (const float4*)(weights + (size_t)lbl * D_DIM);
    float ff = 0.f, ww = 0.f, fw = 0.f;
#pragma unroll
    for (int i = 0; i < 2; ++i) {
        float4 a = f4[lane + i * 64];
        float4 b = w4[lane + i * 64];
        ff += a.x * a.x + a.y * a.y + a.z * a.z + a.w * a.w;
        ww += b.x * b.x + b.y * b.y + b.z * b.z + b.w * b.w;
        fw += a.x * b.x + a.y * b.y + a.z * b.z + a.w * b.w;
    }
#pragma unroll
    for (int off = 32; off > 0; off >>= 1) {
        ff += __shfl_xor(ff, off);
        ww += __shfl_xor(ww, off);
        fw += __shfl_xor(fw, off);
    }
    if (lane == 0) {
        float cg = fw / (sqrtf(ff) * sqrtf(ww));
        float S = rowsum[row];
        float e = expf(scale * cg);
        float p = e / S;
        float Bv = S - e;  // == exp(logit_gt)*(1/p - 1) exactly
        const float PI = 3.14159265358979323846f;
        float marg;
        if (cg > 0.f) {
            marg = asinf(cg) / acosf(cg);  // == pi/(2*theta)-1, no cancellation
        } else {
            float dth = 0.5f * PI - 0.01f;
            marg = PI / (2.0f * dth) - 1.0f;
        }
        size_t o = (size_t)row * C_COLS + lbl;
        cosm[o] = cg;
        logits[o] = logf(Bv * marg);
        pgt[row] = p;
        bvals[row] = Bv;
    }
}

// ---------------------------------------------------------------------------
// Final scalar reductions, one block of 256.
// ---------------------------------------------------------------------------
__global__ __launch_bounds__(256) void finalize_kernel(const float* __restrict__ pgt,
                                                       const float* __restrict__ bvals,
                                                       float* __restrict__ tail,
                                                       float scale) {
    int tid = threadIdx.x;
    float s = 0.f, mn = 1e30f, mx = -1e30f, sb = 0.f;
    for (int i = tid; i < B_ROWS; i += 256) {
        float p = pgt[i];
        s += p;
        mn = fminf(mn, p);
        mx = fmaxf(mx, p);
        sb += bvals[i];
    }
#pragma unroll
    for (int off = 32; off > 0; off >>= 1) {
        s += __shfl_down(s, off);
        mn = fminf(mn, __shfl_down(mn, off));
        mx = fmaxf(mx, __shfl_down(mx, off));
        sb += __shfl_down(sb, off);
    }
    __shared__ float rs[4], rmn[4], rmx[4], rsb[4];
    int wave = tid >> 6;
    if ((tid & 63) == 0) { rs[wave] = s; rmn[wave] = mn; rmx[wave] = mx; rsb[wave] = sb; }
    __syncthreads();
    if (tid == 0) {
        float S = 0.f, MN = 1e30f, MX = -1e30f, SB = 0.f;
        for (int ww = 0; ww < 4; ++ww) {
            S += rs[ww]; MN = fminf(MN, rmn[ww]); MX = fmaxf(MX, rmx[ww]); SB += rsb[ww];
        }
        const float PI = 3.14159265358979323846f;
        tail[0] = S / (float)B_ROWS;
        tail[1] = MN;
        tail[2] = MX;
        float meanB = SB / (float)B_ROWS;
        tail[3] = acosf(logf(meanB / (float)(C_COLS - 1)) / scale) / PI * 180.0f;
        tail[4] = 0.0f;
        tail[5] = 0.0f;
    }
}

// ---------------------------------------------------------------------------
extern "C" void kernel_launch(void* const* d_in, const int* in_sizes, int n_in,
                              void* d_out, int out_size, void* d_ws, size_t ws_size,
                              hipStream_t stream) {
    const float* feat = (const float*)d_in[0];
    const int* label = (const int*)d_in[1];
    const float* weights = (const float*)d_in[2];

    float* out = (float*)d_out;
    float* cos_out = out;
    float* logits_out = out + (size_t)B_ROWS * C_COLS;
    float* tail = out + (size_t)2 * B_ROWS * C_COLS;

    double scale_d = std::sqrt(2.0) * std::log((double)(C_COLS - 1));
    float scale = (float)scale_d;

    const size_t fsz = (size_t)B_ROWS * D_DIM * sizeof(__hip_bfloat16);  // 2 MB
    const size_t wsz = (size_t)WPAD * D_DIM * sizeof(__hip_bfloat16);    // 10.875 MB
    char* wsb = (char*)d_ws;
    __hip_bfloat16* fhi = (__hip_bfloat16*)wsb;
    __hip_bfloat16* whi = (__hip_bfloat16*)(wsb + fsz);
    float* rowsum = (float*)(wsb + fsz + wsz);
    float* pgt = rowsum + B_ROWS;
    float* bv = pgt + B_ROWS;

    normcast_kernel<<<(B_ROWS + WPAD) / 4, 256, 0, stream>>>(feat, weights, fhi, whi,
                                                             rowsum);

    dim3 grid(WPAD / BN, B_ROWS / BM);  // 83 x 16 = 1328
    gemm_bf16_kernel<<<grid, 256, 0, stream>>>(fhi, whi, cos_out, logits_out, rowsum,
                                               scale);

    gt_fix_kernel<<<B_ROWS / 4, 256, 0, stream>>>(feat, weights, label, rowsum, cos_out,
                                                  logits_out, pgt, bv, scale);
    finalize_kernel<<<1, 256, 0, stream>>>(pgt, bv, tail, scale);
}